// Round 4
// baseline (190.933 us; speedup 1.0000x reference)
//
#include <hip/hip_runtime.h>
#include <math.h>

#define FMPX 40
#define NPOS 1600          // 40*40
#define NCLS 80
#define NBOX 8000
#define KDIM 512
#define KC   64            // k-chunk staged in LDS
#define CAP  256           // per-class candidate capacity (expected ~100/class, >12 sigma)

// anchor (w,h) pairs
__constant__ float c_aw[5] = {17.f, 55.f, 92.f, 202.f, 289.f};
__constant__ float c_ah[5] = {25.f, 75.f, 206.f, 21.f, 311.f};

__device__ __forceinline__ float sigf(float x) { return 1.0f / (1.0f + expf(-x)); }

// ---------------------------------------------------------------------------
// K1: the three 1x1-conv GEMMs.
// R3 lesson: inner loop was LDS-pipe-bound; the wave-uniform W ds_read_b128s
// deliver 16B/12cyc (3 cyc/float vs FMA 2 cyc/float) and dominate. Fix: W
// reads go through the SCALAR pipe — og forced uniform via readfirstlane so
// the W pointers are provably wave-uniform -> s_load (free: co-issues with
// VALU + LDS). A stays in LDS (stride-1, conflict-free ds_read_b32).
// grid = (25 M-tiles of 64 pos, 27 N-tiles of 16 outs):
//   nTile 0..24: cls outs (cls_feat); 25/26: the 25 obj+reg outs (reg_feat).
// Per-acc FMA order strictly sequential ascending k — bitwise-identical to
// R1/R2/R3 (protects argmax near-ties; absmax has been stable at 2.0).
// ---------------------------------------------------------------------------
__global__ __launch_bounds__(256) void k_gemm(
    const float* __restrict__ cls_feat, const float* __restrict__ reg_feat,
    const float* __restrict__ w_obj, const float* __restrict__ b_obj,
    const float* __restrict__ w_cls, const float* __restrict__ b_cls,
    const float* __restrict__ w_reg, const float* __restrict__ b_reg,
    float* __restrict__ clsRaw,   // [1600][400]
    float* __restrict__ roRaw)    // [1600][25]: 0..4 obj, 5..24 reg
{
    __shared__ float As[KC * 64];          // 16 KB
    const int mTile = blockIdx.x;          // 0..24
    const int nTile = blockIdx.y;          // 0..26
    const int hw0   = mTile * 64;
    const bool isCls = (nTile < 25);
    const float* feat = isCls ? cls_feat : reg_feat;

    const int pos = threadIdx.x & 63;
    // Wave-uniform by construction (256-thr block = 4 full waves); readfirstlane
    // makes it provably uniform so W loads scalarize to s_load.
    const int og = __builtin_amdgcn_readfirstlane(threadIdx.x >> 6);   // 0..3

    const float* wrow[4];
    float bias[4];
    bool ok[4];
#pragma unroll
    for (int j = 0; j < 4; j++) {
        if (isCls) {
            int o = nTile * 16 + og * 4 + j;
            wrow[j] = w_cls + o * KDIM; bias[j] = b_cls[o]; ok[j] = true;
        } else {
            int o = (nTile - 25) * 16 + og * 4 + j;   // 0..31
            if (o < 5)       { wrow[j] = w_obj + o * KDIM;       bias[j] = b_obj[o];     ok[j] = true; }
            else if (o < 25) { wrow[j] = w_reg + (o - 5) * KDIM; bias[j] = b_reg[o - 5]; ok[j] = true; }
            else             { wrow[j] = w_obj;                  bias[j] = 0.0f;         ok[j] = false; }
        }
    }

    float acc[4] = {0.f, 0.f, 0.f, 0.f};

    for (int kc = 0; kc < KDIM; kc += KC) {
        // stage A chunk [KC][64] (1024 float4; 4 per thread, coalesced)
        for (int i = threadIdx.x * 4; i < KC * 64; i += 256 * 4) {
            int r = i >> 6, c = i & 63;
            *(float4*)&As[i] = *(const float4*)&feat[(kc + r) * NPOS + hw0 + c];
        }
        __syncthreads();

#pragma unroll
        for (int kk = 0; kk < KC; kk += 8) {
            float a[8];
#pragma unroll
            for (int t = 0; t < 8; t++) a[t] = As[(kk + t) * 64 + pos];
#pragma unroll
            for (int j = 0; j < 4; j++) {
                const float* wp = wrow[j] + kc + kk;   // uniform addr -> s_load
                acc[j] += a[0] * wp[0]; acc[j] += a[1] * wp[1];
                acc[j] += a[2] * wp[2]; acc[j] += a[3] * wp[3];
                acc[j] += a[4] * wp[4]; acc[j] += a[5] * wp[5];
                acc[j] += a[6] * wp[6]; acc[j] += a[7] * wp[7];
            }
        }
        __syncthreads();
    }

    const int hw = hw0 + pos;
    if (isCls) {
        float4 rv = make_float4(acc[0] + bias[0], acc[1] + bias[1],
                                acc[2] + bias[2], acc[3] + bias[3]);
        *(float4*)&clsRaw[hw * 400 + nTile * 16 + og * 4] = rv;
    } else {
#pragma unroll
        for (int j = 0; j < 4; j++) {
            int o = (nTile - 25) * 16 + og * 4 + j;
            if (ok[j]) roRaw[hw * 25 + o] = acc[j] + bias[j];
        }
    }
}

// ---------------------------------------------------------------------------
// K2: per-box scores, argmax label, decode, outputs. NO atomics, NO list
// building (R3 suspect: 8000 device-scope atomicAdds on 5 cache lines).
// 2000 blocks x 256 thr; each of the 4 waves handles one box independently.
// ---------------------------------------------------------------------------
__global__ __launch_bounds__(256) void k_box(
    const float* __restrict__ clsRaw, const float* __restrict__ roRaw,
    float* __restrict__ out,          // d_out: [32000 bboxes][8000 score][8000 labels][8000 keep]
    float4* __restrict__ nmsBox, float* __restrict__ nmsArea)
{
    const int n = blockIdx.x * 4 + (threadIdx.x >> 6);   // box index 0..7999
    const int lane = threadIdx.x & 63;
    const int hw = n / 5, a = n % 5;

    const float sobj = sigf(roRaw[hw * 25 + a]);
    const float* cbase = clsRaw + hw * 400 + a * 80;

    // best over classes {lane} and {lane+64 (lane<16)}; ties -> lowest class
    float v = sqrtf(sobj * sigf(cbase[lane]));
    int bi = lane;
    if (lane < 16) {
        float s2 = sqrtf(sobj * sigf(cbase[64 + lane]));
        if (s2 > v) { v = s2; bi = 64 + lane; }
    }
#pragma unroll
    for (int off = 32; off >= 1; off >>= 1) {
        float ov = __shfl_xor(v, off);
        int   oi = __shfl_xor(bi, off);
        if (ov > v || (ov == v && oi < bi)) { v = ov; bi = oi; }
    }

    if (lane == 0) {
        const float* rp = roRaw + hw * 25 + 5 + a * 4;
        float r0 = rp[0], r1 = rp[1], r2 = rp[2], r3 = rp[3];
        float gx = (float)(hw % FMPX), gy = (float)(hw / FMPX);
        float cx = (sigf(r0) + gx) * 32.0f;
        float cy = (sigf(r1) + gy) * 32.0f;
        float wv = expf(r2) * c_aw[a];
        float hv = expf(r3) * c_ah[a];
        float x1 = cx - wv * 0.5f, y1 = cy - hv * 0.5f;
        float x2 = cx + wv * 0.5f, y2 = cy + hv * 0.5f;

        out[n * 4 + 0] = x1; out[n * 4 + 1] = y1;
        out[n * 4 + 2] = x2; out[n * 4 + 3] = y2;
        out[32000 + n] = v;
        out[40000 + n] = (float)bi;
        out[48000 + n] = 0.0f;            // keep init (k_nms sets 1s later)

        // b2: reinterpret x1y1x2y2 as cxcywh (faithful to the reference nms())
        float nx1 = x1 - x2 * 0.5f, ny1 = y1 - y2 * 0.5f;
        float nx2 = x1 + x2 * 0.5f, ny2 = y1 + y2 * 0.5f;
        nmsBox[n]  = make_float4(nx1, ny1, nx2, ny2);
        nmsArea[n] = (nx2 - nx1) * (ny2 - ny1);
    }
}

// ---------------------------------------------------------------------------
// K3: per-class greedy NMS, 80 blocks x 256 thr. Each block scans the dense
// score/label arrays (L2-resident, broadcast to all blocks), compacts its
// class into LDS (LDS atomic — compaction order irrelevant: the bitonic sort
// by (score desc, idx asc) makes the final order fully deterministic ==
// stable argsort(-score) restricted to the class), then greedy suppression.
// ---------------------------------------------------------------------------
__global__ __launch_bounds__(256) void k_nms(
    const float* __restrict__ score, const float* __restrict__ label,
    const float4* __restrict__ nmsBox, const float* __restrict__ nmsArea,
    float* __restrict__ keepOut)
{
    const int c = blockIdx.x;

    __shared__ float ss[CAP];
    __shared__ int   si[CAP];
    __shared__ float bx1[CAP], by1[CAP], bx2[CAP], by2[CAP], bar[CAP];
    __shared__ int   supp[CAP];
    __shared__ int   cnt;

    if (threadIdx.x == 0) cnt = 0;
    __syncthreads();

    for (int i = threadIdx.x; i < NBOX; i += 256) {
        float s = score[i];
        if (s >= 0.3f && (int)label[i] == c) {
            int p = atomicAdd(&cnt, 1);          // LDS atomic
            if (p < CAP) { ss[p] = s; si[p] = i; }
        }
    }
    __syncthreads();

    int m = cnt;
    if (m > CAP) m = CAP;

    // P = next pow2 >= m (min 2); pad with -inf sentinels.
    int P = 2;
    while (P < m) P <<= 1;
    for (int i = threadIdx.x; i < P; i += 256) {
        if (i >= m) { ss[i] = -INFINITY; si[i] = 0x7FFFFFFF; }
    }
    __syncthreads();

    for (int size = 2; size <= P; size <<= 1) {
        for (int stride = size >> 1; stride > 0; stride >>= 1) {
            for (int t = threadIdx.x; t < P / 2; t += 256) {
                int lo = 2 * stride * (t / stride) + (t % stride);
                int hi = lo + stride;
                bool desc = ((lo & size) == 0);
                float slo = ss[lo], shi = ss[hi];
                int   ilo = si[lo], ihi = si[hi];
                bool loBetter = (slo > shi) || (slo == shi && ilo < ihi);
                bool doSwap = desc ? !loBetter : loBetter;
                if (doSwap) { ss[lo] = shi; ss[hi] = slo; si[lo] = ihi; si[hi] = ilo; }
            }
            __syncthreads();
        }
    }

    for (int i = threadIdx.x; i < m; i += 256) {
        int n = si[i];
        float4 b = nmsBox[n];
        bx1[i] = b.x; by1[i] = b.y; bx2[i] = b.z; by2[i] = b.w;
        bar[i] = nmsArea[n];
        supp[i] = 0;
    }
    __syncthreads();

    for (int k = 0; k < m; k++) {
        if (!supp[k]) {
            float kx1 = bx1[k], ky1 = by1[k], kx2 = bx2[k], ky2 = by2[k], ka = bar[k];
            for (int j = k + 1 + threadIdx.x; j < m; j += 256) {
                float xx1 = fmaxf(kx1, bx1[j]);
                float yy1 = fmaxf(ky1, by1[j]);
                float xx2 = fminf(kx2, bx2[j]);
                float yy2 = fminf(ky2, by2[j]);
                float inter = fmaxf(1e-10f, xx2 - xx1) * fmaxf(1e-10f, yy2 - yy1);
                float iou = inter / ((ka + bar[j] - inter) + 1e-14f);
                if (iou > 0.5f) supp[j] = 1;
            }
        }
        __syncthreads();
    }

    for (int j = threadIdx.x; j < m; j += 256) {
        if (!supp[j]) keepOut[si[j]] = 1.0f;
    }
}

// ---------------------------------------------------------------------------
extern "C" void kernel_launch(void* const* d_in, const int* in_sizes, int n_in,
                              void* d_out, int out_size, void* d_ws, size_t ws_size,
                              hipStream_t stream) {
    const float* cls_feat = (const float*)d_in[0];
    const float* reg_feat = (const float*)d_in[1];
    const float* w_obj    = (const float*)d_in[2];
    const float* b_obj    = (const float*)d_in[3];
    const float* w_cls    = (const float*)d_in[4];
    const float* b_cls    = (const float*)d_in[5];
    const float* w_reg    = (const float*)d_in[6];
    const float* b_reg    = (const float*)d_in[7];

    float* out = (float*)d_out;
    float* ws  = (float*)d_ws;

    // workspace layout (floats)
    float*  clsRaw    = ws;                       // 640000
    float*  roRaw     = ws + 640000;              // 40000
    float4* nmsBox    = (float4*)(ws + 680000);   // 32000 floats (16B-aligned offset)
    float*  nmsArea   = ws + 712000;              // 8000
    // total 720000 floats = 2.88 MB

    k_gemm<<<dim3(25, 27), 256, 0, stream>>>(cls_feat, reg_feat,
                                             w_obj, b_obj, w_cls, b_cls, w_reg, b_reg,
                                             clsRaw, roRaw);
    k_box<<<NBOX / 4, 256, 0, stream>>>(clsRaw, roRaw, out, nmsBox, nmsArea);
    k_nms<<<NCLS, 256, 0, stream>>>(out + 32000, out + 40000, nmsBox, nmsArea,
                                    out + 48000);
}

// Round 5
// 149.460 us; speedup vs baseline: 1.2775x; 1.2775x over previous
//
#include <hip/hip_runtime.h>
#include <math.h>

#define FMPX 40
#define NPOS 1600          // 40*40
#define NCLS 80
#define NBOX 8000
#define KDIM 512
#define CAP  256           // per-class candidate capacity (expected ~100/class, >12 sigma)

// anchor (w,h) pairs
__constant__ float c_aw[5] = {17.f, 55.f, 92.f, 202.f, 289.f};
__constant__ float c_ah[5] = {25.f, 75.f, 206.f, 21.f, 311.f};

__device__ __forceinline__ float sigf(float x) { return 1.0f / (1.0f + expf(-x)); }

// ---------------------------------------------------------------------------
// K1: the three 1x1-conv GEMMs.
// R3 lesson: with both A and W in LDS the kernel is LDS-pipe-bound
// (142 cyc LDS vs 64 cyc FMA per 8-k step). R4 lesson: per-step s_load W is
// worse (OOO SMEM forces lgkmcnt(0), serializing scalar-L2 latency).
// R5: A comes straight from GLOBAL (L2-resident 3.3MB < 4MB/XCD — FETCH has
// shown 8x3.3MB all along; coalesced 64x4B; vmcnt pipe), software-pipelined
// two 8-k register buffers deep. W stays in LDS (staged once per block,
// wave-uniform ds_read_b128 broadcast). NO barriers in the K-loop.
// Per-step cost: LDS 96 (W) || VALU ~80 || VMEM ~32  -> ~31us model.
// grid = (25 M-tiles of 64 pos, 27 N-tiles of 16 outs):
//   nTile 0..24: cls outs (cls_feat); 25/26: the 25 obj+reg outs (reg_feat).
// Per-acc FMA order strictly sequential ascending k — bitwise-identical to
// R1-R4 (protects argmax near-ties; absmax stable at 2.0 across rounds).
// ---------------------------------------------------------------------------
__global__ __launch_bounds__(256) void k_gemm(
    const float* __restrict__ cls_feat, const float* __restrict__ reg_feat,
    const float* __restrict__ w_obj, const float* __restrict__ b_obj,
    const float* __restrict__ w_cls, const float* __restrict__ b_cls,
    const float* __restrict__ w_reg, const float* __restrict__ b_reg,
    float* __restrict__ clsRaw,   // [1600][400]
    float* __restrict__ roRaw)    // [1600][25]: 0..4 obj, 5..24 reg
{
    __shared__ float Ws[16 * KDIM];        // 32 KB
    const int mTile = blockIdx.x;          // 0..24
    const int nTile = blockIdx.y;          // 0..26
    const int hw0   = mTile * 64;
    const bool isCls = (nTile < 25);
    const float* feat = isCls ? cls_feat : reg_feat;

    const int pos = threadIdx.x & 63;
    const int og  = threadIdx.x >> 6;      // 0..3 (wave-uniform by construction)

    // A pointer for this lane's position; k strides by NPOS floats.
    const float* ap = feat + hw0 + pos;

    // Initial A prefetch (k=0..15) — independent of W staging, issue early.
    float A0[8], A1[8];
#pragma unroll
    for (int t = 0; t < 8; t++) A0[t] = ap[t * NPOS];
#pragma unroll
    for (int t = 0; t < 8; t++) A1[t] = ap[(8 + t) * NPOS];

    // ---- stage W tile [16][512] (coalesced float4; 8 iters/thread) ----
    for (int i = threadIdx.x * 4; i < 16 * KDIM; i += 256 * 4) {
        int r = i >> 9, k = i & 511;
        const float* src;
        bool valid = true;
        if (isCls) {
            src = w_cls + (nTile * 16 + r) * KDIM + k;
        } else {
            int o = (nTile - 25) * 16 + r;
            if (o < 5)       src = w_obj + o * KDIM + k;
            else if (o < 25) src = w_reg + (o - 5) * KDIM + k;
            else           { src = w_obj; valid = false; }
        }
        float4 v = valid ? *(const float4*)src : make_float4(0.f, 0.f, 0.f, 0.f);
        *(float4*)&Ws[i] = v;
    }

    // ---- per-thread output metadata (wave-uniform) ----
    float bias[4];
    bool ok[4];
#pragma unroll
    for (int j = 0; j < 4; j++) {
        int r = og * 4 + j;                // row within the 16-wide tile
        if (isCls) {
            bias[j] = b_cls[nTile * 16 + r]; ok[j] = true;
        } else {
            int o = (nTile - 25) * 16 + r;
            if (o < 5)       { bias[j] = b_obj[o];     ok[j] = true; }
            else if (o < 25) { bias[j] = b_reg[o - 5]; ok[j] = true; }
            else             { bias[j] = 0.0f;         ok[j] = false; }
        }
    }

    __syncthreads();   // Ws ready; only barrier in the kernel

    float acc[4] = {0.f, 0.f, 0.f, 0.f};
    const float* wsBase = &Ws[(og * 4) * KDIM];

    // Main loop: pairs of 8-k steps; prefetch 16 k ahead. kk = 0..480.
    for (int kk = 0; kk < KDIM - 16; kk += 16) {
        // consume A0 (k = kk..kk+7)
#pragma unroll
        for (int j = 0; j < 4; j++) {
            const float* wp = wsBase + j * KDIM + kk;    // LDS b128 x2, broadcast
            acc[j] += A0[0] * wp[0]; acc[j] += A0[1] * wp[1];
            acc[j] += A0[2] * wp[2]; acc[j] += A0[3] * wp[3];
            acc[j] += A0[4] * wp[4]; acc[j] += A0[5] * wp[5];
            acc[j] += A0[6] * wp[6]; acc[j] += A0[7] * wp[7];
        }
#pragma unroll
        for (int t = 0; t < 8; t++) A0[t] = ap[(kk + 16 + t) * NPOS];
        // consume A1 (k = kk+8..kk+15)
#pragma unroll
        for (int j = 0; j < 4; j++) {
            const float* wp = wsBase + j * KDIM + kk + 8;
            acc[j] += A1[0] * wp[0]; acc[j] += A1[1] * wp[1];
            acc[j] += A1[2] * wp[2]; acc[j] += A1[3] * wp[3];
            acc[j] += A1[4] * wp[4]; acc[j] += A1[5] * wp[5];
            acc[j] += A1[6] * wp[6]; acc[j] += A1[7] * wp[7];
        }
#pragma unroll
        for (int t = 0; t < 8; t++) A1[t] = ap[(kk + 24 + t) * NPOS];
    }
    // tail: k = 496..511, no prefetch
    {
        const int kk = KDIM - 16;
#pragma unroll
        for (int j = 0; j < 4; j++) {
            const float* wp = wsBase + j * KDIM + kk;
            acc[j] += A0[0] * wp[0]; acc[j] += A0[1] * wp[1];
            acc[j] += A0[2] * wp[2]; acc[j] += A0[3] * wp[3];
            acc[j] += A0[4] * wp[4]; acc[j] += A0[5] * wp[5];
            acc[j] += A0[6] * wp[6]; acc[j] += A0[7] * wp[7];
        }
#pragma unroll
        for (int j = 0; j < 4; j++) {
            const float* wp = wsBase + j * KDIM + kk + 8;
            acc[j] += A1[0] * wp[0]; acc[j] += A1[1] * wp[1];
            acc[j] += A1[2] * wp[2]; acc[j] += A1[3] * wp[3];
            acc[j] += A1[4] * wp[4]; acc[j] += A1[5] * wp[5];
            acc[j] += A1[6] * wp[6]; acc[j] += A1[7] * wp[7];
        }
    }

    const int hw = hw0 + pos;
    if (isCls) {
        float4 rv = make_float4(acc[0] + bias[0], acc[1] + bias[1],
                                acc[2] + bias[2], acc[3] + bias[3]);
        *(float4*)&clsRaw[hw * 400 + nTile * 16 + og * 4] = rv;
    } else {
#pragma unroll
        for (int j = 0; j < 4; j++) {
            int o = (nTile - 25) * 16 + og * 4 + j;
            if (ok[j]) roRaw[hw * 25 + o] = acc[j] + bias[j];
        }
    }
}

// ---------------------------------------------------------------------------
// K2: per-box scores, argmax label, decode, outputs. float4 class loads:
// lanes 0..19 each cover 4 classes (in-lane first-max, then cross-lane
// lowest-index tiebreak == jnp.argmax first-max semantics, score arithmetic
// per element unchanged -> bitwise-identical results).
// 2000 blocks x 256 thr; each of the 4 waves handles one box.
// ---------------------------------------------------------------------------
__global__ __launch_bounds__(256) void k_box(
    const float* __restrict__ clsRaw, const float* __restrict__ roRaw,
    float* __restrict__ out,          // d_out: [32000 bboxes][8000 score][8000 labels][8000 keep]
    float4* __restrict__ nmsBox, float* __restrict__ nmsArea,
    float2* __restrict__ sl)          // packed (score,label) for k_nms scan
{
    const int n = blockIdx.x * 4 + (threadIdx.x >> 6);   // box index 0..7999
    const int lane = threadIdx.x & 63;
    const int hw = n / 5, a = n % 5;

    const float sobj = sigf(roRaw[hw * 25 + a]);
    const float* cbase = clsRaw + hw * 400 + a * 80;

    const int l4 = (lane < 20) ? lane : 19;     // clamp for safe address
    float4 cs = *(const float4*)(cbase + l4 * 4);

    // in-lane first-max over classes l4*4 .. l4*4+3 (strict > keeps first)
    float s0 = sqrtf(sobj * sigf(cs.x));
    float s1 = sqrtf(sobj * sigf(cs.y));
    float s2 = sqrtf(sobj * sigf(cs.z));
    float s3 = sqrtf(sobj * sigf(cs.w));
    float v = s0; int bi = l4 * 4;
    if (s1 > v) { v = s1; bi = l4 * 4 + 1; }
    if (s2 > v) { v = s2; bi = l4 * 4 + 2; }
    if (s3 > v) { v = s3; bi = l4 * 4 + 3; }
    if (lane >= 20) { v = -1.0f; bi = 0x7FFFFFFF; }  // scores are always > 0

    // cross-lane: max score, ties -> lowest class
#pragma unroll
    for (int off = 32; off >= 1; off >>= 1) {
        float ov = __shfl_xor(v, off);
        int   oi = __shfl_xor(bi, off);
        if (ov > v || (ov == v && oi < bi)) { v = ov; bi = oi; }
    }

    if (lane == 0) {
        const float* rp = roRaw + hw * 25 + 5 + a * 4;
        float r0 = rp[0], r1 = rp[1], r2 = rp[2], r3 = rp[3];
        float gx = (float)(hw % FMPX), gy = (float)(hw / FMPX);
        float cx = (sigf(r0) + gx) * 32.0f;
        float cy = (sigf(r1) + gy) * 32.0f;
        float wv = expf(r2) * c_aw[a];
        float hv = expf(r3) * c_ah[a];
        float x1 = cx - wv * 0.5f, y1 = cy - hv * 0.5f;
        float x2 = cx + wv * 0.5f, y2 = cy + hv * 0.5f;

        out[n * 4 + 0] = x1; out[n * 4 + 1] = y1;
        out[n * 4 + 2] = x2; out[n * 4 + 3] = y2;
        out[32000 + n] = v;
        out[40000 + n] = (float)bi;
        out[48000 + n] = 0.0f;            // keep init (k_nms sets 1s later)
        sl[n] = make_float2(v, (float)bi);

        // b2: reinterpret x1y1x2y2 as cxcywh (faithful to the reference nms())
        float nx1 = x1 - x2 * 0.5f, ny1 = y1 - y2 * 0.5f;
        float nx2 = x1 + x2 * 0.5f, ny2 = y1 + y2 * 0.5f;
        nmsBox[n]  = make_float4(nx1, ny1, nx2, ny2);
        nmsArea[n] = (nx2 - nx1) * (ny2 - ny1);
    }
}

// ---------------------------------------------------------------------------
// K3: per-class greedy NMS, 80 blocks x 256 thr. Scan packed (score,label)
// (b64 loads, L2-broadcast), compact into LDS (LDS atomic — order irrelevant:
// bitonic sort by (score desc, idx asc) makes the final order deterministic
// == stable argsort(-score) restricted to the class), greedy suppression.
// ---------------------------------------------------------------------------
__global__ __launch_bounds__(256) void k_nms(
    const float2* __restrict__ sl,
    const float4* __restrict__ nmsBox, const float* __restrict__ nmsArea,
    float* __restrict__ keepOut)
{
    const int c = blockIdx.x;

    __shared__ float ss[CAP];
    __shared__ int   si[CAP];
    __shared__ float bx1[CAP], by1[CAP], bx2[CAP], by2[CAP], bar[CAP];
    __shared__ int   supp[CAP];
    __shared__ int   cnt;

    if (threadIdx.x == 0) cnt = 0;
    __syncthreads();

    for (int i = threadIdx.x; i < NBOX; i += 256) {
        float2 p = sl[i];
        if (p.x >= 0.3f && (int)p.y == c) {
            int q = atomicAdd(&cnt, 1);          // LDS atomic
            if (q < CAP) { ss[q] = p.x; si[q] = i; }
        }
    }
    __syncthreads();

    int m = cnt;
    if (m > CAP) m = CAP;

    // P = next pow2 >= m (min 2); pad with -inf sentinels.
    int P = 2;
    while (P < m) P <<= 1;
    for (int i = threadIdx.x; i < P; i += 256) {
        if (i >= m) { ss[i] = -INFINITY; si[i] = 0x7FFFFFFF; }
    }
    __syncthreads();

    for (int size = 2; size <= P; size <<= 1) {
        for (int stride = size >> 1; stride > 0; stride >>= 1) {
            for (int t = threadIdx.x; t < P / 2; t += 256) {
                int lo = 2 * stride * (t / stride) + (t % stride);
                int hi = lo + stride;
                bool desc = ((lo & size) == 0);
                float slo = ss[lo], shi = ss[hi];
                int   ilo = si[lo], ihi = si[hi];
                bool loBetter = (slo > shi) || (slo == shi && ilo < ihi);
                bool doSwap = desc ? !loBetter : loBetter;
                if (doSwap) { ss[lo] = shi; ss[hi] = slo; si[lo] = ihi; si[hi] = ilo; }
            }
            __syncthreads();
        }
    }

    for (int i = threadIdx.x; i < m; i += 256) {
        int n = si[i];
        float4 b = nmsBox[n];
        bx1[i] = b.x; by1[i] = b.y; bx2[i] = b.z; by2[i] = b.w;
        bar[i] = nmsArea[n];
        supp[i] = 0;
    }
    __syncthreads();

    for (int k = 0; k < m; k++) {
        if (!supp[k]) {
            float kx1 = bx1[k], ky1 = by1[k], kx2 = bx2[k], ky2 = by2[k], ka = bar[k];
            for (int j = k + 1 + threadIdx.x; j < m; j += 256) {
                float xx1 = fmaxf(kx1, bx1[j]);
                float yy1 = fmaxf(ky1, by1[j]);
                float xx2 = fminf(kx2, bx2[j]);
                float yy2 = fminf(ky2, by2[j]);
                float inter = fmaxf(1e-10f, xx2 - xx1) * fmaxf(1e-10f, yy2 - yy1);
                float iou = inter / ((ka + bar[j] - inter) + 1e-14f);
                if (iou > 0.5f) supp[j] = 1;
            }
        }
        __syncthreads();
    }

    for (int j = threadIdx.x; j < m; j += 256) {
        if (!supp[j]) keepOut[si[j]] = 1.0f;
    }
}

// ---------------------------------------------------------------------------
extern "C" void kernel_launch(void* const* d_in, const int* in_sizes, int n_in,
                              void* d_out, int out_size, void* d_ws, size_t ws_size,
                              hipStream_t stream) {
    const float* cls_feat = (const float*)d_in[0];
    const float* reg_feat = (const float*)d_in[1];
    const float* w_obj    = (const float*)d_in[2];
    const float* b_obj    = (const float*)d_in[3];
    const float* w_cls    = (const float*)d_in[4];
    const float* b_cls    = (const float*)d_in[5];
    const float* w_reg    = (const float*)d_in[6];
    const float* b_reg    = (const float*)d_in[7];

    float* out = (float*)d_out;
    float* ws  = (float*)d_ws;

    // workspace layout (floats)
    float*  clsRaw    = ws;                       // 640000
    float*  roRaw     = ws + 640000;              // 40000
    float4* nmsBox    = (float4*)(ws + 680000);   // 32000 floats (16B-aligned offset)
    float*  nmsArea   = ws + 712000;              // 8000
    float2* sl        = (float2*)(ws + 720000);   // 16000 floats (8B-aligned)
    // total 736000 floats = 2.944 MB

    k_gemm<<<dim3(25, 27), 256, 0, stream>>>(cls_feat, reg_feat,
                                             w_obj, b_obj, w_cls, b_cls, w_reg, b_reg,
                                             clsRaw, roRaw);
    k_box<<<NBOX / 4, 256, 0, stream>>>(clsRaw, roRaw, out, nmsBox, nmsArea, sl);
    k_nms<<<NCLS, 256, 0, stream>>>(sl, nmsBox, nmsArea, out + 48000);
}